// Round 8
// baseline (2330.583 us; speedup 1.0000x reference)
//
#include <hip/hip_runtime.h>
#include <hip/hip_bf16.h>
#include <stdint.h>

#define TTOK 32768
#define DDIM 512
#define HDIM 2048
#define NEXP 8
#define GBLK 1024      // phase-1 gating blocks; 32 tokens per block (8 per wave)
#define SBLK 128       // phase-2 stats blocks; 256 tokens per block
#define IDXS (TTOK + 256)

typedef __attribute__((ext_vector_type(4))) float f32x4;
typedef __attribute__((ext_vector_type(8))) short bf16x8;

#define GLOAD16(gp, lp)                                                      \
  __builtin_amdgcn_global_load_lds(                                          \
      (const __attribute__((address_space(1))) unsigned int*)(gp),           \
      (__attribute__((address_space(3))) unsigned int*)(lp), 16, 0, 0)

__device__ __forceinline__ ushort f2bf(float f) {
  union { float f; uint32_t u; } cv; cv.f = f;
  uint32_t u = cv.u;
  u = u + 0x7fffu + ((u >> 16) & 1u);
  return (ushort)(u >> 16);
}

__device__ __forceinline__ float bf2f(ushort u) {
  union { uint32_t u; float f; } cv; cv.u = ((uint32_t)u) << 16;
  return cv.f;
}

// gelu via sigmoid: one v_exp + rcp instead of libm tanhf
__device__ __forceinline__ float gelu_fast(float v) {
  float y = 1.5957691216057308f * (v + 0.044715f * v * v * v);
  return v / (1.0f + __expf(-y));
}

// ---------------- weight fp32 -> bf16 convert ----------------
__global__ __launch_bounds__(256) void cvtw_kernel(const float* __restrict__ src,
                                                   ushort* __restrict__ dst, int n4) {
  int i = blockIdx.x * blockDim.x + threadIdx.x;
  if (i >= n4) return;
  float4 v = reinterpret_cast<const float4*>(src)[i];
  ushort4 o;
  o.x = f2bf(v.x); o.y = f2bf(v.y); o.z = f2bf(v.z); o.w = f2bf(v.w);
  reinterpret_cast<ushort4*>(dst)[i] = o;
}

// ---------------- gating phase 1: dots -> logits[T][16], xbf ----------------
// (256,2): wg/wn (128 VGPR) must stay resident (rounds 3/6 lesson: lower caps
// spill ~840MB scratch). Stats moved to phase 2 (they were a 64-lane-redundant
// serial chain).
__global__ __launch_bounds__(256, 2) void gating1_kernel(
    const float* __restrict__ x, const float* __restrict__ gw,
    const float* __restrict__ nw, ushort* __restrict__ xbf,
    float* __restrict__ logits) {
  const int tid = threadIdx.x;
  const int lane = tid & 63;
  const int wave = tid >> 6;

  float wg[NEXP][8], wn[NEXP][8];
#pragma unroll
  for (int e = 0; e < NEXP; ++e) {
    const float4* pg = reinterpret_cast<const float4*>(gw + e * DDIM + lane * 8);
    float4 g0 = pg[0], g1 = pg[1];
    wg[e][0] = g0.x; wg[e][1] = g0.y; wg[e][2] = g0.z; wg[e][3] = g0.w;
    wg[e][4] = g1.x; wg[e][5] = g1.y; wg[e][6] = g1.z; wg[e][7] = g1.w;
    const float4* pq = reinterpret_cast<const float4*>(nw + e * DDIM + lane * 8);
    float4 n0 = pq[0], n1 = pq[1];
    wn[e][0] = n0.x; wn[e][1] = n0.y; wn[e][2] = n0.z; wn[e][3] = n0.w;
    wn[e][4] = n1.x; wn[e][5] = n1.y; wn[e][6] = n1.z; wn[e][7] = n1.w;
  }

  const int t00 = blockIdx.x * 32 + wave * 8;
  for (int it = 0; it < 8; it += 2) {
    float xv[2][8];
#pragma unroll
    for (int u = 0; u < 2; ++u) {
      const int t = t00 + it + u;
      const float4* xp = reinterpret_cast<const float4*>(x + (size_t)t * DDIM + lane * 8);
      float4 x0 = xp[0], x1 = xp[1];
      xv[u][0] = x0.x; xv[u][1] = x0.y; xv[u][2] = x0.z; xv[u][3] = x0.w;
      xv[u][4] = x1.x; xv[u][5] = x1.y; xv[u][6] = x1.z; xv[u][7] = x1.w;
      ushort u8[8];
#pragma unroll
      for (int j = 0; j < 8; ++j) u8[j] = f2bf(xv[u][j]);
      uint4 pack;
      pack.x = (uint32_t)u8[0] | ((uint32_t)u8[1] << 16);
      pack.y = (uint32_t)u8[2] | ((uint32_t)u8[3] << 16);
      pack.z = (uint32_t)u8[4] | ((uint32_t)u8[5] << 16);
      pack.w = (uint32_t)u8[6] | ((uint32_t)u8[7] << 16);
      *reinterpret_cast<uint4*>(xbf + (size_t)t * DDIM + lane * 8) = pack;
    }

    float pg[2][NEXP], pn[2][NEXP];
#pragma unroll
    for (int u = 0; u < 2; ++u)
#pragma unroll
      for (int e = 0; e < NEXP; ++e) { pg[u][e] = 0.f; pn[u][e] = 0.f; }
#pragma unroll
    for (int e = 0; e < NEXP; ++e)
#pragma unroll
      for (int j = 0; j < 8; ++j) {
#pragma unroll
        for (int u = 0; u < 2; ++u) {
          pg[u][e] = fmaf(xv[u][j], wg[e][j], pg[u][e]);
          pn[u][e] = fmaf(xv[u][j], wn[e][j], pn[u][e]);
        }
      }
#pragma unroll
    for (int m = 1; m < 64; m <<= 1) {
#pragma unroll
      for (int u = 0; u < 2; ++u)
#pragma unroll
        for (int e = 0; e < NEXP; ++e) {
          pg[u][e] += __shfl_xor(pg[u][e], m);
          pn[u][e] += __shfl_xor(pn[u][e], m);
        }
    }
    if (lane == 0) {
#pragma unroll
      for (int u = 0; u < 2; ++u) {
        const int t = t00 + it + u;
        float4* lp = reinterpret_cast<float4*>(logits + (size_t)t * 16);
        lp[0] = make_float4(pg[u][0], pg[u][1], pg[u][2], pg[u][3]);
        lp[1] = make_float4(pg[u][4], pg[u][5], pg[u][6], pg[u][7]);
        lp[2] = make_float4(pn[u][0], pn[u][1], pn[u][2], pn[u][3]);
        lp[3] = make_float4(pn[u][4], pn[u][5], pn[u][6], pn[u][7]);
      }
    }
  }
}

// ---------------- gating phase 2: per-token stats/top2 (1 thread = 1 token) --
__global__ void gating2_kernel(
    const float* __restrict__ logits, const float* __restrict__ noise,
    const float* __restrict__ bias, int* __restrict__ cnt,
    int* __restrict__ idxl, int2* __restrict__ slots,
    float2* __restrict__ tokw, float* __restrict__ part) {
  const int tid = threadIdx.x;
  const int lane = tid & 63, wave = tid >> 6;
  const int t = blockIdx.x * 256 + tid;

  const float4* lp = reinterpret_cast<const float4*>(logits + (size_t)t * 16);
  float4 l0 = lp[0], l1 = lp[1], l2 = lp[2], l3 = lp[3];
  float lg[NEXP] = {l0.x, l0.y, l0.z, l0.w, l1.x, l1.y, l1.z, l1.w};
  float nl[NEXP] = {l2.x, l2.y, l2.z, l2.w, l3.x, l3.y, l3.z, l3.w};
  const float4* np = reinterpret_cast<const float4*>(noise + (size_t)t * NEXP);
  float4 z0 = np[0], z1 = np[1];
  float nz[NEXP] = {z0.x, z0.y, z0.z, z0.w, z1.x, z1.y, z1.z, z1.w};
  float bia[NEXP];
#pragma unroll
  for (int e = 0; e < NEXP; ++e) bia[e] = bias[e];

  // penalty softmax (temperature)
  float pa = 0.f, pm[NEXP];
  {
    float sv[NEXP];
#pragma unroll
    for (int e = 0; e < NEXP; ++e) sv[e] = lg[e] * (1.0f / 1.66f);
    float mx = sv[0];
#pragma unroll
    for (int e = 1; e < NEXP; ++e) mx = fmaxf(mx, sv[e]);
    float ssum = 0.f, pv[NEXP];
#pragma unroll
    for (int e = 0; e < NEXP; ++e) { pv[e] = __expf(sv[e] - mx); ssum += pv[e]; }
    float sinv = 1.f / ssum;
#pragma unroll
    for (int e = 0; e < NEXP; ++e) {
      float pe = pv[e] * sinv;
      pa += pe * (1.f - pe);
      pm[e] = pe;
    }
  }
  // z-loss
  float z2;
  {
    float mg = lg[0];
#pragma unroll
    for (int e = 1; e < NEXP; ++e) mg = fmaxf(mg, lg[e]);
    float es = 0.f;
#pragma unroll
    for (int e = 0; e < NEXP; ++e) es += __expf(lg[e] - mg);
    float lse = mg + __logf(es);
    z2 = lse * lse;
  }
  // noisy logits + top2
  float g2[NEXP];
#pragma unroll
  for (int e = 0; e < NEXP; ++e) {
    float s = nl[e];
    float sp = fmaxf(s, 0.f) + __logf(1.f + __expf(-fabsf(s)));
    g2[e] = lg[e] + nz[e] * sp + bia[e];
  }
  float v1 = g2[0]; int i1 = 0;
#pragma unroll
  for (int e = 1; e < NEXP; ++e) if (g2[e] > v1) { v1 = g2[e]; i1 = e; }
  float v2 = -3.4e38f; int i2 = 0;
#pragma unroll
  for (int e = 0; e < NEXP; ++e) if (e != i1 && g2[e] > v2) { v2 = g2[e]; i2 = e; }
  float dd = __expf(v2 - v1);
  float w1 = 1.f / (1.f + dd);
  float w2 = dd / (1.f + dd);
  // router probs
  float rp[NEXP];
  {
    float mr = g2[0];
#pragma unroll
    for (int e = 1; e < NEXP; ++e) mr = fmaxf(mr, g2[e]);
    float rs = 0.f, er[NEXP];
#pragma unroll
    for (int e = 0; e < NEXP; ++e) { er[e] = __expf(g2[e] - mr); rs += er[e]; }
    float rinv = 1.f / rs;
#pragma unroll
    for (int e = 0; e < NEXP; ++e) rp[e] = er[e] * rinv;
  }

  // block stats reduction (34 values butterfly over 64, then cross-wave)
  float loc[34];
  loc[0] = pa; loc[1] = z2;
#pragma unroll
  for (int e = 0; e < NEXP; ++e) {
    loc[2 + e]  = pm[e];
    loc[10 + e] = (e == i1 ? w1 : 0.f) + (e == i2 ? w2 : 0.f);
    loc[18 + e] = rp[e];
    loc[26 + e] = (e == i1) ? 1.f : 0.f;
  }
#pragma unroll
  for (int m = 1; m < 64; m <<= 1) {
#pragma unroll
    for (int s = 0; s < 34; ++s) loc[s] += __shfl_xor(loc[s], m);
  }
  __shared__ float red[4][34];
  if (lane == 0) {
#pragma unroll
    for (int s = 0; s < 34; ++s) red[wave][s] = loc[s];
  }
  // list appends via per-block LDS aggregation
  __shared__ int lcnt[NEXP], gbase[NEXP];
  if (tid < NEXP) lcnt[tid] = 0;
  __syncthreads();
  int p1 = atomicAdd(&lcnt[i1], 1);
  int p2 = atomicAdd(&lcnt[i2], 1);
  __syncthreads();
  if (tid < NEXP) gbase[tid] = atomicAdd(&cnt[tid], lcnt[tid]);
  if (tid < 34) {
    float s = red[0][tid] + red[1][tid] + red[2][tid] + red[3][tid];
    part[(size_t)tid * SBLK + blockIdx.x] = s;
  }
  __syncthreads();
  int q1 = gbase[i1] + p1, q2 = gbase[i2] + p2;
  idxl[i1 * IDXS + q1] = t;
  idxl[i2 * IDXS + q2] = t;
  slots[t] = make_int2((i1 << 16) | q1, (i2 << 16) | q2);
  tokw[t] = make_float2(w1, w2);
}

// ---------------- finalize: aux + offsets + list padding (to 256) -----------
__global__ __launch_bounds__(256) void finalize_kernel(
    const float* __restrict__ part, const int* __restrict__ cnt,
    int* __restrict__ offs, int* __restrict__ idxl,
    float* __restrict__ aux_out) {
  __shared__ float sums[34];
  __shared__ float red[4][34];
  __shared__ int roundc[NEXP], base[NEXP];
  const int tid = threadIdx.x;
  const int lane = tid & 63, wave = tid >> 6;

  float loc[34];
#pragma unroll
  for (int s = 0; s < 34; ++s) loc[s] = 0.f;
  for (int b = tid; b < SBLK; b += 256) {
#pragma unroll
    for (int s = 0; s < 34; ++s) loc[s] += part[(size_t)s * SBLK + b];
  }
#pragma unroll
  for (int m = 1; m < 64; m <<= 1) {
#pragma unroll
    for (int s = 0; s < 34; ++s) loc[s] += __shfl_xor(loc[s], m);
  }
  if (lane == 0) {
#pragma unroll
    for (int s = 0; s < 34; ++s) red[wave][s] = loc[s];
  }
  if (tid == 0) {
    int acc = 0;
    for (int e = 0; e < NEXP; ++e) {
      int r = (cnt[e] + 255) & ~255;
      roundc[e] = r; base[e] = acc; acc += r;
    }
  }
  __syncthreads();
  if (tid < 34) sums[tid] = red[0][tid] + red[1][tid] + red[2][tid] + red[3][tid];
  __syncthreads();
  for (int i = tid; i < NEXP * 256; i += 256) {
    int e = i >> 8, k = i & 255;
    int pos = cnt[e] + k;
    if (pos < roundc[e]) idxl[e * IDXS + pos] = 0;
  }
  if (tid < NEXP) offs[tid] = base[tid];
  if (tid == 0) {
    const float Tf = (float)TTOK;
    float pa = sums[0] / (Tf * 8.f);
    float pbm = 0.f;
    for (int e = 0; e < NEXP; ++e) { float pm = sums[2 + e] / Tf; pbm += pm * (1.f - pm); }
    float pb = 1.f / 8.f - pbm / 8.f;
    float penalty = (pa + pb) * 0.01f;
    float z = 0.001f * sums[1] / Tf;
    float mean = 0.f;
    for (int e = 0; e < NEXP; ++e) mean += sums[10 + e];
    mean /= 8.f;
    float var = 0.f;
    for (int e = 0; e < NEXP; ++e) { float d = sums[10 + e] - mean; var += d * d; }
    var /= 8.f;
    float il = 0.01f * var / (mean * mean);
    float ld = 0.f;
    for (int e = 0; e < NEXP; ++e) ld += (sums[26 + e] / Tf) * (sums[18 + e] / Tf);
    ld *= 0.01f * 8.f;
    aux_out[0] = penalty + z + il + ld;
  }
}

// ============ GEMM kernels: 256x128 tile, 8 waves, 48KB single-buffer =======
// Staged bytes/FLOP 1.45x less than 128^2 (diagnosed L2->LDS traffic as the
// co-limiter: ~50% of L2 and ~45% of LDS BW at round-7). 3 blocks/CU.
// XOR swizzle preserved: LDS slot s of row r holds global chunk s^(r&7).

// ---------------- GEMM1: h = gelu(x[idx] @ Wfc^T + b) ----------------
__global__ __launch_bounds__(512, 6) void gemm1_kernel(
    const ushort* __restrict__ xbf, const ushort* __restrict__ wfc,
    const float* __restrict__ fcb, const int* __restrict__ idxl,
    const int* __restrict__ cnt, const int* __restrict__ offs,
    ushort* __restrict__ h, int hbase, int HC) {
  const int e = blockIdx.z;
  const int count = cnt[e];
  const int rounded = (count + 255) & ~255;
  const int mt = blockIdx.x;
  if (mt * 256 >= rounded) return;
  const int nt = blockIdx.y;
  const int tid = threadIdx.x;
  const int lane = tid & 63, wave = tid >> 6;
  const int wm = wave >> 1, wn = wave & 1;   // 4x2 wave grid over 256x128

  __shared__ ushort As[256][64];
  __shared__ ushort Bs[128][64];

  const int srow = tid >> 3;                        // 0..63
  const int csw8 = (((tid & 7) ^ (srow & 7)) << 3); // swizzled global chunk
  const int dst8 = ((tid & 7) << 3);                // linear LDS chunk

  int gA[4];
  const ushort* bbase = wfc + (size_t)e * (HDIM * DDIM) +
                        (size_t)(hbase + nt * 128) * DDIM;
#pragma unroll
  for (int r = 0; r < 4; ++r)
    gA[r] = idxl[e * IDXS + mt * 256 + srow + r * 64];

  f32x4 acc[4][4];
#pragma unroll
  for (int m = 0; m < 4; ++m)
#pragma unroll
    for (int n = 0; n < 4; ++n)
      acc[m][n] = (f32x4){0.f, 0.f, 0.f, 0.f};

  const int NK = DDIM / 64;
  for (int kt = 0; kt < NK; ++kt) {
    const int koff = kt * 64;
#pragma unroll
    for (int r = 0; r < 4; ++r)
      GLOAD16(xbf + (size_t)gA[r] * DDIM + koff + csw8, &As[srow + r * 64][dst8]);
#pragma unroll
    for (int r = 0; r < 2; ++r)
      GLOAD16(bbase + (size_t)(srow + r * 64) * DDIM + koff + csw8, &Bs[srow + r * 64][dst8]);
    asm volatile("s_waitcnt vmcnt(0)" ::: "memory");
    __syncthreads();
#pragma unroll
    for (int ks = 0; ks < 2; ++ks) {
      const int ch = (((ks << 2) | (lane >> 4)) ^ (lane & 7)) << 3;
      bf16x8 af[4], bfr[4];
#pragma unroll
      for (int m = 0; m < 4; ++m)
        af[m] = *reinterpret_cast<const bf16x8*>(&As[wm * 64 + m * 16 + (lane & 15)][ch]);
#pragma unroll
      for (int n = 0; n < 4; ++n)
        bfr[n] = *reinterpret_cast<const bf16x8*>(&Bs[wn * 64 + n * 16 + (lane & 15)][ch]);
#pragma unroll
      for (int m = 0; m < 4; ++m)
#pragma unroll
        for (int n = 0; n < 4; ++n)
          acc[m][n] = __builtin_amdgcn_mfma_f32_16x16x32_bf16(af[m], bfr[n], acc[m][n], 0, 0, 0);
    }
    __syncthreads();
  }

  const int hb = offs[e];
#pragma unroll
  for (int n = 0; n < 4; ++n) {
    const int col = wn * 64 + n * 16 + (lane & 15);
    const int gcol = hbase + nt * 128 + col;
    const float bterm = fcb[e * HDIM + gcol];
#pragma unroll
    for (int m = 0; m < 4; ++m) {
#pragma unroll
      for (int j = 0; j < 4; ++j) {
        const int row = mt * 256 + wm * 64 + m * 16 + ((lane >> 4) << 2) + j;
        float v = acc[m][n][j] + bterm;
        h[(size_t)(hb + row) * HC + (nt * 128 + col)] = f2bf(gelu_fast(v));
      }
    }
  }
}

// ---------------- GEMM2: scratch[slot] (+)= h @ Wproj^T + b ----------------
__global__ __launch_bounds__(512, 6) void gemm2_kernel(
    const ushort* __restrict__ h, const ushort* __restrict__ wpj,
    const float* __restrict__ pjb, const int* __restrict__ cnt,
    const int* __restrict__ offs, ushort* __restrict__ scratch,
    int hbase, int HC, int first_chunk) {
  const int e = blockIdx.z;
  const int count = cnt[e];
  const int rounded = (count + 255) & ~255;
  const int mt = blockIdx.x;
  if (mt * 256 >= rounded) return;
  const int nt = blockIdx.y;
  const int tid = threadIdx.x;
  const int lane = tid & 63, wave = tid >> 6;
  const int wm = wave >> 1, wn = wave & 1;

  __shared__ ushort As[256][64];
  __shared__ ushort Bs[128][64];

  const int srow = tid >> 3;
  const int csw8 = (((tid & 7) ^ (srow & 7)) << 3);
  const int dst8 = ((tid & 7) << 3);
  const int hb = offs[e];

  const ushort* abase = h + (size_t)(hb + mt * 256) * HC;
  const ushort* bbase = wpj + (size_t)e * (DDIM * HDIM) +
                        (size_t)(nt * 128) * HDIM + hbase;

  f32x4 acc[4][4];
#pragma unroll
  for (int m = 0; m < 4; ++m)
#pragma unroll
    for (int n = 0; n < 4; ++n)
      acc[m][n] = (f32x4){0.f, 0.f, 0.f, 0.f};

  const int NK = HC / 64;
  for (int kt = 0; kt < NK; ++kt) {
    const int koff = kt * 64;
#pragma unroll
    for (int r = 0; r < 4; ++r)
      GLOAD16(abase + (size_t)(srow + r * 64) * HC + koff + csw8, &As[srow + r * 64][dst8]);
#pragma unroll
    for (int r = 0; r < 2; ++r)
      GLOAD16(bbase + (size_t)(srow + r * 64) * HDIM + koff + csw8, &Bs[srow + r * 64][dst8]);
    asm volatile("s_waitcnt vmcnt(0)" ::: "memory");
    __syncthreads();
#pragma unroll
    for (int ks = 0; ks < 2; ++ks) {
      const int ch = (((ks << 2) | (lane >> 4)) ^ (lane & 7)) << 3;
      bf16x8 af[4], bfr[4];
#pragma unroll
      for (int m = 0; m < 4; ++m)
        af[m] = *reinterpret_cast<const bf16x8*>(&As[wm * 64 + m * 16 + (lane & 15)][ch]);
#pragma unroll
      for (int n = 0; n < 4; ++n)
        bfr[n] = *reinterpret_cast<const bf16x8*>(&Bs[wn * 64 + n * 16 + (lane & 15)][ch]);
#pragma unroll
      for (int m = 0; m < 4; ++m)
#pragma unroll
        for (int n = 0; n < 4; ++n)
          acc[m][n] = __builtin_amdgcn_mfma_f32_16x16x32_bf16(af[m], bfr[n], acc[m][n], 0, 0, 0);
    }
    __syncthreads();
  }

#pragma unroll
  for (int n = 0; n < 4; ++n) {
    const int col = nt * 128 + wn * 64 + n * 16 + (lane & 15);
    const float bterm = pjb[e * DDIM + col];
#pragma unroll
    for (int m = 0; m < 4; ++m) {
#pragma unroll
      for (int j = 0; j < 4; ++j) {
        const size_t row = (size_t)(hb + mt * 256 + wm * 64 + m * 16 + ((lane >> 4) << 2) + j);
        ushort* p = scratch + row * DDIM + col;
        float v = acc[m][n][j];
        if (first_chunk) v += bterm;
        else v += bf2f(*p);
        *p = f2bf(v);
      }
    }
  }
}

// ---------------- combine: out[t] = w1*row1 + w2*row2 ----------------
__global__ __launch_bounds__(256, 8) void combine_kernel(
    const ushort* __restrict__ scratch, const int* __restrict__ offs,
    const int2* __restrict__ slots, const float2* __restrict__ tokw,
    float* __restrict__ out) {
  const int lane = threadIdx.x & 63;
  const int wave = threadIdx.x >> 6;
  const int t = blockIdx.x * 4 + wave;
  int2 s = slots[t];
  float2 w = tokw[t];
  const int r1 = offs[s.x >> 16] + (s.x & 0xFFFF);
  const int r2 = offs[s.y >> 16] + (s.y & 0xFFFF);
  bf16x8 a = *reinterpret_cast<const bf16x8*>(scratch + (size_t)r1 * DDIM + lane * 8);
  bf16x8 b = *reinterpret_cast<const bf16x8*>(scratch + (size_t)r2 * DDIM + lane * 8);
  float r[8];
#pragma unroll
  for (int j = 0; j < 8; ++j)
    r[j] = w.x * bf2f((ushort)a[j]) + w.y * bf2f((ushort)b[j]);
  float4* op = reinterpret_cast<float4*>(out + (size_t)t * DDIM + lane * 8);
  op[0] = make_float4(r[0], r[1], r[2], r[3]);
  op[1] = make_float4(r[4], r[5], r[6], r[7]);
}

extern "C" void kernel_launch(void* const* d_in, const int* in_sizes, int n_in,
                              void* d_out, int out_size, void* d_ws, size_t ws_size,
                              hipStream_t stream) {
  const float* x    = (const float*)d_in[0];
  const float* gw   = (const float*)d_in[1];
  const float* nw   = (const float*)d_in[2];
  const float* bias = (const float*)d_in[3];
  const float* fcw  = (const float*)d_in[4];
  const float* fcb  = (const float*)d_in[5];
  const float* pjw  = (const float*)d_in[6];
  const float* pjb  = (const float*)d_in[7];
  const float* noise = (const float*)d_in[8];
  float* out = (float*)d_out;

  char* ws = (char*)d_ws;
  size_t o = 0;
  auto alloc = [&](size_t bytes) -> char* {
    char* p = ws + o;
    o += (bytes + 255) & ~(size_t)255;
    return p;
  };
  ushort* xbf    = (ushort*)alloc((size_t)TTOK * DDIM * 2);
  ushort* wfcb   = (ushort*)alloc((size_t)NEXP * HDIM * DDIM * 2);
  ushort* wpjb   = (ushort*)alloc((size_t)NEXP * DDIM * HDIM * 2);
  float*  logits = (float*)alloc((size_t)TTOK * 16 * 4);
  int*    idxl   = (int*)alloc((size_t)NEXP * IDXS * 4);
  int2*   slots  = (int2*)alloc((size_t)TTOK * 8);
  float2* tokw   = (float2*)alloc((size_t)TTOK * 8);
  int*    cnt    = (int*)alloc(256);
  int*    offs   = (int*)alloc(256);
  float*  part   = (float*)alloc(34 * SBLK * 4);
  ushort* scr    = (ushort*)alloc((size_t)(2 * TTOK + 2048) * DDIM * 2);
  size_t fixed = o;

  int NCH = 16;
  const int chs[5] = {1, 2, 4, 8, 16};
  for (int ci = 0; ci < 5; ++ci) {
    size_t need = fixed + (size_t)(2 * TTOK + 2048) * (size_t)(HDIM / chs[ci]) * 2;
    if (need <= ws_size) { NCH = chs[ci]; break; }
  }
  const int HC = HDIM / NCH;
  ushort* h = (ushort*)alloc((size_t)(2 * TTOK + 2048) * HC * 2);

  hipMemsetAsync(cnt, 0, 32, stream);

  cvtw_kernel<<<8192, 256, 0, stream>>>(fcw, wfcb, NEXP * HDIM * DDIM / 4);
  cvtw_kernel<<<8192, 256, 0, stream>>>(pjw, wpjb, NEXP * DDIM * HDIM / 4);
  gating1_kernel<<<GBLK, 256, 0, stream>>>(x, gw, nw, xbf, logits);
  gating2_kernel<<<SBLK, 256, 0, stream>>>(logits, noise, bias, cnt, idxl, slots, tokw, part);
  finalize_kernel<<<1, 256, 0, stream>>>(part, cnt, offs, idxl, out + ((size_t)out_size - 1));

  for (int c = 0; c < NCH; ++c) {
    gemm1_kernel<<<dim3(128, HC / 128, NEXP), 512, 0, stream>>>(
        xbf, wfcb, fcb, idxl, cnt, offs, h, c * HC, HC);
    gemm2_kernel<<<dim3(128, 4, NEXP), 512, 0, stream>>>(
        h, wpjb, pjb, cnt, offs, scr, c * HC, HC, c == 0);
  }
  combine_kernel<<<TTOK / 4, 256, 0, stream>>>(scr, offs, slots, tokw, out);
}

// Round 9
// 691.844 us; speedup vs baseline: 3.3687x; 3.3687x over previous
//
#include <hip/hip_runtime.h>
#include <hip/hip_bf16.h>
#include <stdint.h>

#define TTOK 32768
#define DDIM 512
#define HDIM 2048
#define NEXP 8
#define GBLK 1024      // phase-1 gating blocks; 32 tokens per block (8 per wave)
#define SBLK 128       // phase-2 stats blocks; 256 tokens per block
#define IDXS (TTOK + 256)

typedef __attribute__((ext_vector_type(4))) float f32x4;
typedef __attribute__((ext_vector_type(8))) short bf16x8;

#define GLOAD16(gp, lp)                                                      \
  __builtin_amdgcn_global_load_lds(                                          \
      (const __attribute__((address_space(1))) unsigned int*)(gp),           \
      (__attribute__((address_space(3))) unsigned int*)(lp), 16, 0, 0)

__device__ __forceinline__ ushort f2bf(float f) {
  union { float f; uint32_t u; } cv; cv.f = f;
  uint32_t u = cv.u;
  u = u + 0x7fffu + ((u >> 16) & 1u);
  return (ushort)(u >> 16);
}

__device__ __forceinline__ float bf2f(ushort u) {
  union { uint32_t u; float f; } cv; cv.u = ((uint32_t)u) << 16;
  return cv.f;
}

// gelu via sigmoid: one v_exp + rcp instead of libm tanhf
__device__ __forceinline__ float gelu_fast(float v) {
  float y = 1.5957691216057308f * (v + 0.044715f * v * v * v);
  return v / (1.0f + __expf(-y));
}

// ---------------- weight fp32 -> bf16 convert ----------------
__global__ __launch_bounds__(256) void cvtw_kernel(const float* __restrict__ src,
                                                   ushort* __restrict__ dst, int n4) {
  int i = blockIdx.x * blockDim.x + threadIdx.x;
  if (i >= n4) return;
  float4 v = reinterpret_cast<const float4*>(src)[i];
  ushort4 o;
  o.x = f2bf(v.x); o.y = f2bf(v.y); o.z = f2bf(v.z); o.w = f2bf(v.w);
  reinterpret_cast<ushort4*>(dst)[i] = o;
}

// ---------------- gating phase 1: dots -> logits[T][16], xbf ----------------
// (256,2): wg/wn (128 VGPR) must stay resident (rounds 3/6 lesson: lower caps
// spill ~840MB scratch).
__global__ __launch_bounds__(256, 2) void gating1_kernel(
    const float* __restrict__ x, const float* __restrict__ gw,
    const float* __restrict__ nw, ushort* __restrict__ xbf,
    float* __restrict__ logits) {
  const int tid = threadIdx.x;
  const int lane = tid & 63;
  const int wave = tid >> 6;

  float wg[NEXP][8], wn[NEXP][8];
#pragma unroll
  for (int e = 0; e < NEXP; ++e) {
    const float4* pg = reinterpret_cast<const float4*>(gw + e * DDIM + lane * 8);
    float4 g0 = pg[0], g1 = pg[1];
    wg[e][0] = g0.x; wg[e][1] = g0.y; wg[e][2] = g0.z; wg[e][3] = g0.w;
    wg[e][4] = g1.x; wg[e][5] = g1.y; wg[e][6] = g1.z; wg[e][7] = g1.w;
    const float4* pq = reinterpret_cast<const float4*>(nw + e * DDIM + lane * 8);
    float4 n0 = pq[0], n1 = pq[1];
    wn[e][0] = n0.x; wn[e][1] = n0.y; wn[e][2] = n0.z; wn[e][3] = n0.w;
    wn[e][4] = n1.x; wn[e][5] = n1.y; wn[e][6] = n1.z; wn[e][7] = n1.w;
  }

  const int t00 = blockIdx.x * 32 + wave * 8;
  for (int it = 0; it < 8; it += 2) {
    float xv[2][8];
#pragma unroll
    for (int u = 0; u < 2; ++u) {
      const int t = t00 + it + u;
      const float4* xp = reinterpret_cast<const float4*>(x + (size_t)t * DDIM + lane * 8);
      float4 x0 = xp[0], x1 = xp[1];
      xv[u][0] = x0.x; xv[u][1] = x0.y; xv[u][2] = x0.z; xv[u][3] = x0.w;
      xv[u][4] = x1.x; xv[u][5] = x1.y; xv[u][6] = x1.z; xv[u][7] = x1.w;
      ushort u8[8];
#pragma unroll
      for (int j = 0; j < 8; ++j) u8[j] = f2bf(xv[u][j]);
      uint4 pack;
      pack.x = (uint32_t)u8[0] | ((uint32_t)u8[1] << 16);
      pack.y = (uint32_t)u8[2] | ((uint32_t)u8[3] << 16);
      pack.z = (uint32_t)u8[4] | ((uint32_t)u8[5] << 16);
      pack.w = (uint32_t)u8[6] | ((uint32_t)u8[7] << 16);
      *reinterpret_cast<uint4*>(xbf + (size_t)t * DDIM + lane * 8) = pack;
    }

    float pg[2][NEXP], pn[2][NEXP];
#pragma unroll
    for (int u = 0; u < 2; ++u)
#pragma unroll
      for (int e = 0; e < NEXP; ++e) { pg[u][e] = 0.f; pn[u][e] = 0.f; }
#pragma unroll
    for (int e = 0; e < NEXP; ++e)
#pragma unroll
      for (int j = 0; j < 8; ++j) {
#pragma unroll
        for (int u = 0; u < 2; ++u) {
          pg[u][e] = fmaf(xv[u][j], wg[e][j], pg[u][e]);
          pn[u][e] = fmaf(xv[u][j], wn[e][j], pn[u][e]);
        }
      }
#pragma unroll
    for (int m = 1; m < 64; m <<= 1) {
#pragma unroll
      for (int u = 0; u < 2; ++u)
#pragma unroll
        for (int e = 0; e < NEXP; ++e) {
          pg[u][e] += __shfl_xor(pg[u][e], m);
          pn[u][e] += __shfl_xor(pn[u][e], m);
        }
    }
    if (lane == 0) {
#pragma unroll
      for (int u = 0; u < 2; ++u) {
        const int t = t00 + it + u;
        float4* lp = reinterpret_cast<float4*>(logits + (size_t)t * 16);
        lp[0] = make_float4(pg[u][0], pg[u][1], pg[u][2], pg[u][3]);
        lp[1] = make_float4(pg[u][4], pg[u][5], pg[u][6], pg[u][7]);
        lp[2] = make_float4(pn[u][0], pn[u][1], pn[u][2], pn[u][3]);
        lp[3] = make_float4(pn[u][4], pn[u][5], pn[u][6], pn[u][7]);
      }
    }
  }
}

// ---------------- gating phase 2: per-token stats/top2 (1 thread = 1 token) --
__global__ void gating2_kernel(
    const float* __restrict__ logits, const float* __restrict__ noise,
    const float* __restrict__ bias, int* __restrict__ cnt,
    int* __restrict__ idxl, int2* __restrict__ slots,
    float2* __restrict__ tokw, float* __restrict__ part) {
  const int tid = threadIdx.x;
  const int lane = tid & 63, wave = tid >> 6;
  const int t = blockIdx.x * 256 + tid;

  const float4* lp = reinterpret_cast<const float4*>(logits + (size_t)t * 16);
  float4 l0 = lp[0], l1 = lp[1], l2 = lp[2], l3 = lp[3];
  float lg[NEXP] = {l0.x, l0.y, l0.z, l0.w, l1.x, l1.y, l1.z, l1.w};
  float nl[NEXP] = {l2.x, l2.y, l2.z, l2.w, l3.x, l3.y, l3.z, l3.w};
  const float4* np = reinterpret_cast<const float4*>(noise + (size_t)t * NEXP);
  float4 z0 = np[0], z1 = np[1];
  float nz[NEXP] = {z0.x, z0.y, z0.z, z0.w, z1.x, z1.y, z1.z, z1.w};
  float bia[NEXP];
#pragma unroll
  for (int e = 0; e < NEXP; ++e) bia[e] = bias[e];

  float pa = 0.f, pm[NEXP];
  {
    float sv[NEXP];
#pragma unroll
    for (int e = 0; e < NEXP; ++e) sv[e] = lg[e] * (1.0f / 1.66f);
    float mx = sv[0];
#pragma unroll
    for (int e = 1; e < NEXP; ++e) mx = fmaxf(mx, sv[e]);
    float ssum = 0.f, pv[NEXP];
#pragma unroll
    for (int e = 0; e < NEXP; ++e) { pv[e] = __expf(sv[e] - mx); ssum += pv[e]; }
    float sinv = 1.f / ssum;
#pragma unroll
    for (int e = 0; e < NEXP; ++e) {
      float pe = pv[e] * sinv;
      pa += pe * (1.f - pe);
      pm[e] = pe;
    }
  }
  float z2;
  {
    float mg = lg[0];
#pragma unroll
    for (int e = 1; e < NEXP; ++e) mg = fmaxf(mg, lg[e]);
    float es = 0.f;
#pragma unroll
    for (int e = 0; e < NEXP; ++e) es += __expf(lg[e] - mg);
    float lse = mg + __logf(es);
    z2 = lse * lse;
  }
  float g2[NEXP];
#pragma unroll
  for (int e = 0; e < NEXP; ++e) {
    float s = nl[e];
    float sp = fmaxf(s, 0.f) + __logf(1.f + __expf(-fabsf(s)));
    g2[e] = lg[e] + nz[e] * sp + bia[e];
  }
  float v1 = g2[0]; int i1 = 0;
#pragma unroll
  for (int e = 1; e < NEXP; ++e) if (g2[e] > v1) { v1 = g2[e]; i1 = e; }
  float v2 = -3.4e38f; int i2 = 0;
#pragma unroll
  for (int e = 0; e < NEXP; ++e) if (e != i1 && g2[e] > v2) { v2 = g2[e]; i2 = e; }
  float dd = __expf(v2 - v1);
  float w1 = 1.f / (1.f + dd);
  float w2 = dd / (1.f + dd);
  float rp[NEXP];
  {
    float mr = g2[0];
#pragma unroll
    for (int e = 1; e < NEXP; ++e) mr = fmaxf(mr, g2[e]);
    float rs = 0.f, er[NEXP];
#pragma unroll
    for (int e = 0; e < NEXP; ++e) { er[e] = __expf(g2[e] - mr); rs += er[e]; }
    float rinv = 1.f / rs;
#pragma unroll
    for (int e = 0; e < NEXP; ++e) rp[e] = er[e] * rinv;
  }

  float loc[34];
  loc[0] = pa; loc[1] = z2;
#pragma unroll
  for (int e = 0; e < NEXP; ++e) {
    loc[2 + e]  = pm[e];
    loc[10 + e] = (e == i1 ? w1 : 0.f) + (e == i2 ? w2 : 0.f);
    loc[18 + e] = rp[e];
    loc[26 + e] = (e == i1) ? 1.f : 0.f;
  }
#pragma unroll
  for (int m = 1; m < 64; m <<= 1) {
#pragma unroll
    for (int s = 0; s < 34; ++s) loc[s] += __shfl_xor(loc[s], m);
  }
  __shared__ float red[4][34];
  if (lane == 0) {
#pragma unroll
    for (int s = 0; s < 34; ++s) red[wave][s] = loc[s];
  }
  __shared__ int lcnt[NEXP], gbase[NEXP];
  if (tid < NEXP) lcnt[tid] = 0;
  __syncthreads();
  int p1 = atomicAdd(&lcnt[i1], 1);
  int p2 = atomicAdd(&lcnt[i2], 1);
  __syncthreads();
  if (tid < NEXP) gbase[tid] = atomicAdd(&cnt[tid], lcnt[tid]);
  if (tid < 34) {
    float s = red[0][tid] + red[1][tid] + red[2][tid] + red[3][tid];
    part[(size_t)tid * SBLK + blockIdx.x] = s;
  }
  __syncthreads();
  int q1 = gbase[i1] + p1, q2 = gbase[i2] + p2;
  idxl[i1 * IDXS + q1] = t;
  idxl[i2 * IDXS + q2] = t;
  slots[t] = make_int2((i1 << 16) | q1, (i2 << 16) | q2);
  tokw[t] = make_float2(w1, w2);
}

// ---------------- finalize: aux + offsets + list padding (to 256) -----------
__global__ __launch_bounds__(256) void finalize_kernel(
    const float* __restrict__ part, const int* __restrict__ cnt,
    int* __restrict__ offs, int* __restrict__ idxl,
    float* __restrict__ aux_out) {
  __shared__ float sums[34];
  __shared__ float red[4][34];
  __shared__ int roundc[NEXP], base[NEXP];
  const int tid = threadIdx.x;
  const int lane = tid & 63, wave = tid >> 6;

  float loc[34];
#pragma unroll
  for (int s = 0; s < 34; ++s) loc[s] = 0.f;
  for (int b = tid; b < SBLK; b += 256) {
#pragma unroll
    for (int s = 0; s < 34; ++s) loc[s] += part[(size_t)s * SBLK + b];
  }
#pragma unroll
  for (int m = 1; m < 64; m <<= 1) {
#pragma unroll
    for (int s = 0; s < 34; ++s) loc[s] += __shfl_xor(loc[s], m);
  }
  if (lane == 0) {
#pragma unroll
    for (int s = 0; s < 34; ++s) red[wave][s] = loc[s];
  }
  if (tid == 0) {
    int acc = 0;
    for (int e = 0; e < NEXP; ++e) {
      int r = (cnt[e] + 255) & ~255;
      roundc[e] = r; base[e] = acc; acc += r;
    }
  }
  __syncthreads();
  if (tid < 34) sums[tid] = red[0][tid] + red[1][tid] + red[2][tid] + red[3][tid];
  __syncthreads();
  for (int i = tid; i < NEXP * 256; i += 256) {
    int e = i >> 8, k = i & 255;
    int pos = cnt[e] + k;
    if (pos < roundc[e]) idxl[e * IDXS + pos] = 0;
  }
  if (tid < NEXP) offs[tid] = base[tid];
  if (tid == 0) {
    const float Tf = (float)TTOK;
    float pa = sums[0] / (Tf * 8.f);
    float pbm = 0.f;
    for (int e = 0; e < NEXP; ++e) { float pm = sums[2 + e] / Tf; pbm += pm * (1.f - pm); }
    float pb = 1.f / 8.f - pbm / 8.f;
    float penalty = (pa + pb) * 0.01f;
    float z = 0.001f * sums[1] / Tf;
    float mean = 0.f;
    for (int e = 0; e < NEXP; ++e) mean += sums[10 + e];
    mean /= 8.f;
    float var = 0.f;
    for (int e = 0; e < NEXP; ++e) { float d = sums[10 + e] - mean; var += d * d; }
    var /= 8.f;
    float il = 0.01f * var / (mean * mean);
    float ld = 0.f;
    for (int e = 0; e < NEXP; ++e) ld += (sums[26 + e] / Tf) * (sums[18 + e] / Tf);
    ld *= 0.01f * 8.f;
    aux_out[0] = penalty + z + il + ld;
  }
}

// ============ GEMM kernels: 256x128 tile, 8 waves, 48KB single-buffer =======
// ROUND-8 BUG: __launch_bounds__(512,6) -> VGPR cap 85 -> accumulator spilled
// (VGPR_Count=40, 1GB traffic/dispatch). RULE: GEMM needs cap >=128, i.e.
// 2nd arg <=4 at 512 threads. (512,4): cap 128 fits the ~90-reg live set;
// LDS 48KB allows 3 blocks/CU, VGPR gives ~2.

// ---------------- GEMM1: h = gelu(x[idx] @ Wfc^T + b) ----------------
__global__ __launch_bounds__(512, 4) void gemm1_kernel(
    const ushort* __restrict__ xbf, const ushort* __restrict__ wfc,
    const float* __restrict__ fcb, const int* __restrict__ idxl,
    const int* __restrict__ cnt, const int* __restrict__ offs,
    ushort* __restrict__ h, int hbase, int HC) {
  const int e = blockIdx.z;
  const int count = cnt[e];
  const int rounded = (count + 255) & ~255;
  const int mt = blockIdx.x;
  if (mt * 256 >= rounded) return;
  const int nt = blockIdx.y;
  const int tid = threadIdx.x;
  const int lane = tid & 63, wave = tid >> 6;
  const int wm = wave >> 1, wn = wave & 1;   // 4x2 wave grid over 256x128

  __shared__ ushort As[256][64];
  __shared__ ushort Bs[128][64];

  const int srow = tid >> 3;                        // 0..63
  const int csw8 = (((tid & 7) ^ (srow & 7)) << 3); // swizzled global chunk
  const int dst8 = ((tid & 7) << 3);                // linear LDS chunk

  int gA[4];
  const ushort* bbase = wfc + (size_t)e * (HDIM * DDIM) +
                        (size_t)(hbase + nt * 128) * DDIM;
#pragma unroll
  for (int r = 0; r < 4; ++r)
    gA[r] = idxl[e * IDXS + mt * 256 + srow + r * 64];

  f32x4 acc[4][4];
#pragma unroll
  for (int m = 0; m < 4; ++m)
#pragma unroll
    for (int n = 0; n < 4; ++n)
      acc[m][n] = (f32x4){0.f, 0.f, 0.f, 0.f};

  const int NK = DDIM / 64;
  for (int kt = 0; kt < NK; ++kt) {
    const int koff = kt * 64;
#pragma unroll
    for (int r = 0; r < 4; ++r)
      GLOAD16(xbf + (size_t)gA[r] * DDIM + koff + csw8, &As[srow + r * 64][dst8]);
#pragma unroll
    for (int r = 0; r < 2; ++r)
      GLOAD16(bbase + (size_t)(srow + r * 64) * DDIM + koff + csw8, &Bs[srow + r * 64][dst8]);
    asm volatile("s_waitcnt vmcnt(0)" ::: "memory");
    __syncthreads();
#pragma unroll
    for (int ks = 0; ks < 2; ++ks) {
      const int ch = (((ks << 2) | (lane >> 4)) ^ (lane & 7)) << 3;
      bf16x8 af[4], bfr[4];
#pragma unroll
      for (int m = 0; m < 4; ++m)
        af[m] = *reinterpret_cast<const bf16x8*>(&As[wm * 64 + m * 16 + (lane & 15)][ch]);
#pragma unroll
      for (int n = 0; n < 4; ++n)
        bfr[n] = *reinterpret_cast<const bf16x8*>(&Bs[wn * 64 + n * 16 + (lane & 15)][ch]);
#pragma unroll
      for (int m = 0; m < 4; ++m)
#pragma unroll
        for (int n = 0; n < 4; ++n)
          acc[m][n] = __builtin_amdgcn_mfma_f32_16x16x32_bf16(af[m], bfr[n], acc[m][n], 0, 0, 0);
    }
    __syncthreads();
  }

  const int hb = offs[e];
#pragma unroll
  for (int n = 0; n < 4; ++n) {
    const int col = wn * 64 + n * 16 + (lane & 15);
    const int gcol = hbase + nt * 128 + col;
    const float bterm = fcb[e * HDIM + gcol];
#pragma unroll
    for (int m = 0; m < 4; ++m) {
#pragma unroll
      for (int j = 0; j < 4; ++j) {
        const int row = mt * 256 + wm * 64 + m * 16 + ((lane >> 4) << 2) + j;
        float v = acc[m][n][j] + bterm;
        h[(size_t)(hb + row) * HC + (nt * 128 + col)] = f2bf(gelu_fast(v));
      }
    }
  }
}

// ---------------- GEMM2: scratch[slot] (+)= h @ Wproj^T + b ----------------
__global__ __launch_bounds__(512, 4) void gemm2_kernel(
    const ushort* __restrict__ h, const ushort* __restrict__ wpj,
    const float* __restrict__ pjb, const int* __restrict__ cnt,
    const int* __restrict__ offs, ushort* __restrict__ scratch,
    int hbase, int HC, int first_chunk) {
  const int e = blockIdx.z;
  const int count = cnt[e];
  const int rounded = (count + 255) & ~255;
  const int mt = blockIdx.x;
  if (mt * 256 >= rounded) return;
  const int nt = blockIdx.y;
  const int tid = threadIdx.x;
  const int lane = tid & 63, wave = tid >> 6;
  const int wm = wave >> 1, wn = wave & 1;

  __shared__ ushort As[256][64];
  __shared__ ushort Bs[128][64];

  const int srow = tid >> 3;
  const int csw8 = (((tid & 7) ^ (srow & 7)) << 3);
  const int dst8 = ((tid & 7) << 3);
  const int hb = offs[e];

  const ushort* abase = h + (size_t)(hb + mt * 256) * HC;
  const ushort* bbase = wpj + (size_t)e * (DDIM * HDIM) +
                        (size_t)(nt * 128) * HDIM + hbase;

  f32x4 acc[4][4];
#pragma unroll
  for (int m = 0; m < 4; ++m)
#pragma unroll
    for (int n = 0; n < 4; ++n)
      acc[m][n] = (f32x4){0.f, 0.f, 0.f, 0.f};

  const int NK = HC / 64;
  for (int kt = 0; kt < NK; ++kt) {
    const int koff = kt * 64;
#pragma unroll
    for (int r = 0; r < 4; ++r)
      GLOAD16(abase + (size_t)(srow + r * 64) * HC + koff + csw8, &As[srow + r * 64][dst8]);
#pragma unroll
    for (int r = 0; r < 2; ++r)
      GLOAD16(bbase + (size_t)(srow + r * 64) * HDIM + koff + csw8, &Bs[srow + r * 64][dst8]);
    asm volatile("s_waitcnt vmcnt(0)" ::: "memory");
    __syncthreads();
#pragma unroll
    for (int ks = 0; ks < 2; ++ks) {
      const int ch = (((ks << 2) | (lane >> 4)) ^ (lane & 7)) << 3;
      bf16x8 af[4], bfr[4];
#pragma unroll
      for (int m = 0; m < 4; ++m)
        af[m] = *reinterpret_cast<const bf16x8*>(&As[wm * 64 + m * 16 + (lane & 15)][ch]);
#pragma unroll
      for (int n = 0; n < 4; ++n)
        bfr[n] = *reinterpret_cast<const bf16x8*>(&Bs[wn * 64 + n * 16 + (lane & 15)][ch]);
#pragma unroll
      for (int m = 0; m < 4; ++m)
#pragma unroll
        for (int n = 0; n < 4; ++n)
          acc[m][n] = __builtin_amdgcn_mfma_f32_16x16x32_bf16(af[m], bfr[n], acc[m][n], 0, 0, 0);
    }
    __syncthreads();
  }

#pragma unroll
  for (int n = 0; n < 4; ++n) {
    const int col = nt * 128 + wn * 64 + n * 16 + (lane & 15);
    const float bterm = pjb[e * DDIM + col];
#pragma unroll
    for (int m = 0; m < 4; ++m) {
#pragma unroll
      for (int j = 0; j < 4; ++j) {
        const size_t row = (size_t)(hb + mt * 256 + wm * 64 + m * 16 + ((lane >> 4) << 2) + j);
        ushort* p = scratch + row * DDIM + col;
        float v = acc[m][n][j];
        if (first_chunk) v += bterm;
        else v += bf2f(*p);
        *p = f2bf(v);
      }
    }
  }
}

// ---------------- combine: out[t] = w1*row1 + w2*row2 ----------------
__global__ __launch_bounds__(256, 8) void combine_kernel(
    const ushort* __restrict__ scratch, const int* __restrict__ offs,
    const int2* __restrict__ slots, const float2* __restrict__ tokw,
    float* __restrict__ out) {
  const int lane = threadIdx.x & 63;
  const int wave = threadIdx.x >> 6;
  const int t = blockIdx.x * 4 + wave;
  int2 s = slots[t];
  float2 w = tokw[t];
  const int r1 = offs[s.x >> 16] + (s.x & 0xFFFF);
  const int r2 = offs[s.y >> 16] + (s.y & 0xFFFF);
  bf16x8 a = *reinterpret_cast<const bf16x8*>(scratch + (size_t)r1 * DDIM + lane * 8);
  bf16x8 b = *reinterpret_cast<const bf16x8*>(scratch + (size_t)r2 * DDIM + lane * 8);
  float r[8];
#pragma unroll
  for (int j = 0; j < 8; ++j)
    r[j] = w.x * bf2f((ushort)a[j]) + w.y * bf2f((ushort)b[j]);
  float4* op = reinterpret_cast<float4*>(out + (size_t)t * DDIM + lane * 8);
  op[0] = make_float4(r[0], r[1], r[2], r[3]);
  op[1] = make_float4(r[4], r[5], r[6], r[7]);
}

extern "C" void kernel_launch(void* const* d_in, const int* in_sizes, int n_in,
                              void* d_out, int out_size, void* d_ws, size_t ws_size,
                              hipStream_t stream) {
  const float* x    = (const float*)d_in[0];
  const float* gw   = (const float*)d_in[1];
  const float* nw   = (const float*)d_in[2];
  const float* bias = (const float*)d_in[3];
  const float* fcw  = (const float*)d_in[4];
  const float* fcb  = (const float*)d_in[5];
  const float* pjw  = (const float*)d_in[6];
  const float* pjb  = (const float*)d_in[7];
  const float* noise = (const float*)d_in[8];
  float* out = (float*)d_out;

  char* ws = (char*)d_ws;
  size_t o = 0;
  auto alloc = [&](size_t bytes) -> char* {
    char* p = ws + o;
    o += (bytes + 255) & ~(size_t)255;
    return p;
  };
  ushort* xbf    = (ushort*)alloc((size_t)TTOK * DDIM * 2);
  ushort* wfcb   = (ushort*)alloc((size_t)NEXP * HDIM * DDIM * 2);
  ushort* wpjb   = (ushort*)alloc((size_t)NEXP * DDIM * HDIM * 2);
  float*  logits = (float*)alloc((size_t)TTOK * 16 * 4);
  int*    idxl   = (int*)alloc((size_t)NEXP * IDXS * 4);
  int2*   slots  = (int2*)alloc((size_t)TTOK * 8);
  float2* tokw   = (float2*)alloc((size_t)TTOK * 8);
  int*    cnt    = (int*)alloc(256);
  int*    offs   = (int*)alloc(256);
  float*  part   = (float*)alloc(34 * SBLK * 4);
  ushort* scr    = (ushort*)alloc((size_t)(2 * TTOK + 2048) * DDIM * 2);
  size_t fixed = o;

  int NCH = 16;
  const int chs[5] = {1, 2, 4, 8, 16};
  for (int ci = 0; ci < 5; ++ci) {
    size_t need = fixed + (size_t)(2 * TTOK + 2048) * (size_t)(HDIM / chs[ci]) * 2;
    if (need <= ws_size) { NCH = chs[ci]; break; }
  }
  const int HC = HDIM / NCH;
  ushort* h = (ushort*)alloc((size_t)(2 * TTOK + 2048) * HC * 2);

  hipMemsetAsync(cnt, 0, 32, stream);

  cvtw_kernel<<<8192, 256, 0, stream>>>(fcw, wfcb, NEXP * HDIM * DDIM / 4);
  cvtw_kernel<<<8192, 256, 0, stream>>>(pjw, wpjb, NEXP * DDIM * HDIM / 4);
  gating1_kernel<<<GBLK, 256, 0, stream>>>(x, gw, nw, xbf, logits);
  gating2_kernel<<<SBLK, 256, 0, stream>>>(logits, noise, bias, cnt, idxl, slots, tokw, part);
  finalize_kernel<<<1, 256, 0, stream>>>(part, cnt, offs, idxl, out + ((size_t)out_size - 1));

  for (int c = 0; c < NCH; ++c) {
    gemm1_kernel<<<dim3(128, HC / 128, NEXP), 512, 0, stream>>>(
        xbf, wfcb, fcb, idxl, cnt, offs, h, c * HC, HC);
    gemm2_kernel<<<dim3(128, 4, NEXP), 512, 0, stream>>>(
        h, wpjb, pjb, cnt, offs, scr, c * HC, HC, c == 0);
  }
  combine_kernel<<<TTOK / 4, 256, 0, stream>>>(scr, offs, slots, tokw, out);
}